// Round 19
// baseline (162.818 us; speedup 1.0000x reference)
//
#include <hip/hip_runtime.h>

using u16 = unsigned short;
using u32 = unsigned int;
using u64 = unsigned long long;

typedef __attribute__((ext_vector_type(8))) short bf16x8;
typedef __attribute__((ext_vector_type(4))) float f32x4;

// Problem constants (from reference)
constexpr int Nn  = 50000;   // nodes
constexpr int Ee  = 800000;  // edges
constexpr int Bb  = 256;     // graphs
constexpr int INF = 32;      // input feature dim
constexpr int Hh  = 96;      // hidden dim
constexpr float BN_EPS = 1e-5f;

// Binned CSR build parameters
constexpr int BINW = 128;                      // nodes per bin
constexpr int NBIN = (Nn + BINW - 1) / BINW;   // 391
constexpr int P1B  = 256;                      // pass-1 blocks
constexpr int EPB  = Ee / P1B;                 // 3125 edges per block (exact)
constexpr int CAP  = 40;                       // per (block,bin) capacity (mean 8, ~8e-15 tail)
constexpr int P3IT = P1B * CAP / 256;          // 40 iterations per p3 thread

// Transposed bf16 weight tables: wT[j][k], k-contiguous, row stride 104 u16.
constexpr int WROW   = 104;
constexpr int WMAT   = 96 * WROW;              // 9984 u16 per matrix
constexpr int WB_TOT = 6 * WMAT;               // 59904 u16

// ---------------- bf16 helpers (rne) ----------------
__device__ __forceinline__ float bfL(u32 u) { return __uint_as_float(u << 16); }
__device__ __forceinline__ float bfH(u32 u) { return __uint_as_float(u & 0xFFFF0000u); }
__device__ __forceinline__ u32 f2bfb(float f) {            // rounded bf16 bits (low 16)
    u32 b = __float_as_uint(f);
    return (b + 0x7FFFu + ((b >> 16) & 1u)) >> 16;
}
__device__ __forceinline__ float bf2f(u16 u) { return __uint_as_float(((u32)u) << 16); }

// ---------------------------------------------------------------------------
// Combined init: x -> bf16 table; weights -> bf16 transposed tables;
// zero bintot + pooled. Grid 1024: blocks [0,782) do x, [782,1024) do w.
// ---------------------------------------------------------------------------
__global__ void init_kernel(const float* __restrict__ x, u16* __restrict__ xb,
                            const float* __restrict__ w1i, const float* __restrict__ w1o,
                            const float* __restrict__ w2i, const float* __restrict__ w2o,
                            const float* __restrict__ w3i, const float* __restrict__ w3o,
                            u16* __restrict__ wb,
                            int* __restrict__ bintot, float* __restrict__ pooled) {
    const int gid = blockIdx.x * 256 + threadIdx.x;
    if (gid < NBIN) bintot[gid] = 0;
    if (gid < Bb * Hh) pooled[gid] = 0.0f;

    if (blockIdx.x < 782) {
        const int total = Nn * INF / 8;
        for (int i = gid; i < total; i += 782 * 256) {
            const float4 a = ((const float4*)x)[2 * i];
            const float4 b = ((const float4*)x)[2 * i + 1];
            uint4 R;
            R.x = f2bfb(a.x) | (f2bfb(a.y) << 16);
            R.y = f2bfb(a.z) | (f2bfb(a.w) << 16);
            R.z = f2bfb(b.x) | (f2bfb(b.y) << 16);
            R.w = f2bfb(b.z) | (f2bfb(b.w) << 16);
            ((uint4*)xb)[i] = R;
        }
    } else {
        const int wid = (blockIdx.x - 782) * 256 + threadIdx.x;   // u32 word index
        if (wid < WB_TOT / 2) {
            const int mat = wid / (WMAT / 2);
            const int rem = wid % (WMAT / 2);
            const int j   = rem / (WROW / 2);
            const int k   = (rem % (WROW / 2)) * 2;
            const float* src; int din;
            switch (mat) {
                case 0: src = w1i; din = 32; break;
                case 1: src = w1o; din = 96; break;
                case 2: src = w2i; din = 96; break;
                case 3: src = w2o; din = 96; break;
                case 4: src = w3i; din = 96; break;
                default: src = w3o; din = 96; break;
            }
            const u32 lo = (k     < din) ? f2bfb(src[(long)k * 96 + j])       : 0u;
            const u32 hi = (k + 1 < din) ? f2bfb(src[(long)(k + 1) * 96 + j]) : 0u;
            ((u32*)wb)[wid] = lo | (hi << 16);
        }
    }
}

// ---------------------------------------------------------------------------
// CSR build pass 1: bin edges into per-(block,bin) private regions.
// ---------------------------------------------------------------------------
__global__ __launch_bounds__(256)
void p1_bin_kernel(const int* __restrict__ src, const int* __restrict__ dst,
                   u32* __restrict__ binbuf, int* __restrict__ counts,
                   int* __restrict__ bintot) {
    __shared__ int cur[NBIN];
    const int b = blockIdx.x, tid = threadIdx.x;
    for (int k = tid; k < NBIN; k += 256) cur[k] = 0;
    __syncthreads();
    const long e0 = (long)b * EPB;
    for (int i = tid; i < EPB; i += 256) {
        const long e = e0 + i;
        const int d = dst[e];
        const int k = d >> 7;                              // BINW = 128
        const int pos = atomicAdd(&cur[k], 1);
        binbuf[((long)b * NBIN + k) * CAP + pos] = ((u32)(d & 127) << 16) | (u32)src[e];
    }
    __syncthreads();
    for (int k = tid; k < NBIN; k += 256) {
        const int c = cur[k];
        counts[k * P1B + b] = c;
        if (c) atomicAdd(&bintot[k], c);
    }
}

// ---------------------------------------------------------------------------
// CSR build pass 2: scan of bintot -> binbase; rowptr[N] = E. 512 threads.
// ---------------------------------------------------------------------------
__global__ void p2_binscan_kernel(const int* __restrict__ bintot, int* __restrict__ binbase,
                                  int* __restrict__ rowptr) {
    __shared__ int ps[512];
    const int t = threadIdx.x;
    const int v = (t < NBIN) ? bintot[t] : 0;
    ps[t] = v;
    __syncthreads();
    for (int d = 1; d < 512; d <<= 1) {
        int u = (t >= d) ? ps[t - d] : 0;
        __syncthreads();
        if (t >= d) ps[t] += u;
        __syncthreads();
    }
    if (t < NBIN) binbase[t] = ps[t] - v;   // exclusive prefix
    if (t == 0) rowptr[Nn] = Ee;
}

// ---------------------------------------------------------------------------
// CSR build pass 3: one block per bin; payloads register-cached.
// ---------------------------------------------------------------------------
__global__ __launch_bounds__(256)
void p3_binsort_kernel(const u32* __restrict__ binbuf, const int* __restrict__ counts,
                       const int* __restrict__ binbase, int* __restrict__ rowptr,
                       u16* __restrict__ csr) {
    __shared__ int cnt[P1B];
    __shared__ int lhist[BINW];
    __shared__ int lpref[BINW];
    const int k = blockIdx.x, tid = threadIdx.x;

    for (int b = tid; b < P1B; b += 256) cnt[b] = counts[k * P1B + b];
    if (tid < BINW) lhist[tid] = 0;
    __syncthreads();

    u32 pv[P3IT];
    u64 vmask = 0;
    #pragma unroll
    for (int it = 0; it < P3IT; ++it) {
        const int flat = tid + it * 256;
        const int b = flat / CAP, i = flat % CAP;
        if (i < cnt[b]) {
            const u32 v = binbuf[((long)b * NBIN + k) * CAP + i];
            pv[it] = v;
            vmask |= 1ull << it;
            atomicAdd(&lhist[v >> 16], 1);
        }
    }
    __syncthreads();

    if (tid < BINW) lpref[tid] = lhist[tid];
    __syncthreads();
    for (int d = 1; d < BINW; d <<= 1) {
        int u = 0;
        if (tid < BINW && tid >= d) u = lpref[tid - d];
        __syncthreads();
        if (tid < BINW && tid >= d) lpref[tid] += u;
        __syncthreads();
    }
    if (tid < BINW) lpref[tid] -= lhist[tid];

    const int base = binbase[k];
    const int node = k * BINW + tid;
    if (tid < BINW && node < Nn) rowptr[node] = base + lpref[tid];
    if (tid < BINW) lhist[tid] = 0;                 // reuse as cursor
    __syncthreads();

    #pragma unroll
    for (int it = 0; it < P3IT; ++it) {
        if (vmask & (1ull << it)) {
            const u32 v = pv[it];
            const int dl = v >> 16;
            const int pos = base + lpref[dl] + atomicAdd(&lhist[dl], 1);
            csr[pos] = (u16)(v & 0xFFFFu);
        }
    }
}

// ---------------------------------------------------------------------------
// FULL GIN LAYER with MFMA GEMMs. 32-node tile, 384 threads (6 waves).
// Gather: 8x edge unroll with uint4-vectorized csr index loads.
// POOL=true (layer 3): fused graph pooling.
// ---------------------------------------------------------------------------
template<int DIN, bool POOL>
__global__ __launch_bounds__(384, 4)
void layer_kernel(const u16* __restrict__ hsrc, const int* __restrict__ rowptr,
                  const u16* __restrict__ csr,
                  const u16* __restrict__ wbg1, const u16* __restrict__ wbg2,
                  const float* __restrict__ b_in,
                  const float* __restrict__ gamma, const float* __restrict__ beta,
                  const float* __restrict__ rmean, const float* __restrict__ rvar,
                  const float* __restrict__ b_out,
                  u16* __restrict__ out,
                  const int* __restrict__ batch, float* __restrict__ pooled) {
    constexpr int TILE = 32;
    constexpr int XST  = 104;                 // u16 stride (208B rows)
    __shared__ __align__(16) u16 wT[96 * XST];
    __shared__ __align__(16) u16 xs[TILE * XST];

    const int tid = threadIdx.x;
    const int nbase = blockIdx.x * TILE;

    // stage wT(w_in)
    for (int i = tid; i < 96 * XST / 8; i += 384)
        ((uint4*)wT)[i] = ((const uint4*)wbg1)[i];

    // ---- gather phase: 12 lanes per node (uint4 each), 8x edge unroll ----
    {
        const int grp = tid / 12, ln = tid % 12;
        const int node = nbase + grp;
        if (node < Nn) {
            const int e0 = rowptr[node], e1 = rowptr[node + 1];
            if constexpr (DIN == 96) {
                const uint4* h4 = (const uint4*)hsrc;     // row = 12 uint4
                float a0, a1, a2, a3, a4, a5, a6, a7;
                {
                    const uint4 U = h4[(long)node * 12 + ln];
                    a0 = bfL(U.x); a1 = bfH(U.x); a2 = bfL(U.y); a3 = bfH(U.y);
                    a4 = bfL(U.z); a5 = bfH(U.z); a6 = bfL(U.w); a7 = bfH(U.w);
                }
                int e = e0;
                if ((e & 1) && e < e1) {                  // peel to even alignment
                    const uint4 U = h4[(long)csr[e] * 12 + ln];
                    a0 += bfL(U.x); a1 += bfH(U.x); a2 += bfL(U.y); a3 += bfH(U.y);
                    a4 += bfL(U.z); a5 += bfH(U.z); a6 += bfL(U.w); a7 += bfH(U.w);
                    ++e;
                }
                for (; e + 8 <= e1; e += 8) {
                    const uint4 I = *(const uint4*)&csr[e];   // 8 u16 indices, 4B-aligned
                    uint4 U[8];
                    U[0] = h4[(long)(I.x & 0xFFFFu) * 12 + ln];
                    U[1] = h4[(long)(I.x >> 16)     * 12 + ln];
                    U[2] = h4[(long)(I.y & 0xFFFFu) * 12 + ln];
                    U[3] = h4[(long)(I.y >> 16)     * 12 + ln];
                    U[4] = h4[(long)(I.z & 0xFFFFu) * 12 + ln];
                    U[5] = h4[(long)(I.z >> 16)     * 12 + ln];
                    U[6] = h4[(long)(I.w & 0xFFFFu) * 12 + ln];
                    U[7] = h4[(long)(I.w >> 16)     * 12 + ln];
                    #pragma unroll
                    for (int q = 0; q < 8; ++q) {
                        a0 += bfL(U[q].x); a1 += bfH(U[q].x);
                        a2 += bfL(U[q].y); a3 += bfH(U[q].y);
                        a4 += bfL(U[q].z); a5 += bfH(U[q].z);
                        a6 += bfL(U[q].w); a7 += bfH(U[q].w);
                    }
                }
                for (; e + 2 <= e1; e += 2) {
                    const u32 I = *(const u32*)&csr[e];
                    const uint4 Ua = h4[(long)(I & 0xFFFFu) * 12 + ln];
                    const uint4 Ub = h4[(long)(I >> 16)     * 12 + ln];
                    a0 += bfL(Ua.x); a1 += bfH(Ua.x); a2 += bfL(Ua.y); a3 += bfH(Ua.y);
                    a4 += bfL(Ua.z); a5 += bfH(Ua.z); a6 += bfL(Ua.w); a7 += bfH(Ua.w);
                    a0 += bfL(Ub.x); a1 += bfH(Ub.x); a2 += bfL(Ub.y); a3 += bfH(Ub.y);
                    a4 += bfL(Ub.z); a5 += bfH(Ub.z); a6 += bfL(Ub.w); a7 += bfH(Ub.w);
                }
                if (e < e1) {
                    const uint4 U = h4[(long)csr[e] * 12 + ln];
                    a0 += bfL(U.x); a1 += bfH(U.x); a2 += bfL(U.y); a3 += bfH(U.y);
                    a4 += bfL(U.z); a5 += bfH(U.z); a6 += bfL(U.w); a7 += bfH(U.w);
                }
                u32* xp = (u32*)&xs[grp * XST + ln * 8];
                xp[0] = f2bfb(a0) | (f2bfb(a1) << 16);
                xp[1] = f2bfb(a2) | (f2bfb(a3) << 16);
                xp[2] = f2bfb(a4) | (f2bfb(a5) << 16);
                xp[3] = f2bfb(a6) | (f2bfb(a7) << 16);
            } else {                                      // DIN == 32: 8 lanes/node
                if (ln < 8) {
                    const uint2* h2 = (const uint2*)hsrc; // row = 8 uint2
                    float a0, a1, a2, a3;
                    {
                        const uint2 U = h2[(long)node * 8 + ln];
                        a0 = bfL(U.x); a1 = bfH(U.x); a2 = bfL(U.y); a3 = bfH(U.y);
                    }
                    int e = e0;
                    if ((e & 1) && e < e1) {
                        const uint2 U = h2[(long)csr[e] * 8 + ln];
                        a0 += bfL(U.x); a1 += bfH(U.x); a2 += bfL(U.y); a3 += bfH(U.y);
                        ++e;
                    }
                    for (; e + 8 <= e1; e += 8) {
                        const uint4 I = *(const uint4*)&csr[e];
                        uint2 U[8];
                        U[0] = h2[(long)(I.x & 0xFFFFu) * 8 + ln];
                        U[1] = h2[(long)(I.x >> 16)     * 8 + ln];
                        U[2] = h2[(long)(I.y & 0xFFFFu) * 8 + ln];
                        U[3] = h2[(long)(I.y >> 16)     * 8 + ln];
                        U[4] = h2[(long)(I.z & 0xFFFFu) * 8 + ln];
                        U[5] = h2[(long)(I.z >> 16)     * 8 + ln];
                        U[6] = h2[(long)(I.w & 0xFFFFu) * 8 + ln];
                        U[7] = h2[(long)(I.w >> 16)     * 8 + ln];
                        #pragma unroll
                        for (int q = 0; q < 8; ++q) {
                            a0 += bfL(U[q].x); a1 += bfH(U[q].x);
                            a2 += bfL(U[q].y); a3 += bfH(U[q].y);
                        }
                    }
                    for (; e < e1; ++e) {
                        const uint2 U = h2[(long)csr[e] * 8 + ln];
                        a0 += bfL(U.x); a1 += bfH(U.x); a2 += bfL(U.y); a3 += bfH(U.y);
                    }
                    u32* xp = (u32*)&xs[grp * XST + ln * 4];
                    xp[0] = f2bfb(a0) | (f2bfb(a1) << 16);
                    xp[1] = f2bfb(a2) | (f2bfb(a3) << 16);
                }
            }
        } else {
            if constexpr (DIN == 96) {
                u32* xp = (u32*)&xs[grp * XST + ln * 8];
                xp[0] = xp[1] = xp[2] = xp[3] = 0u;
            } else if (ln < 8) {
                u32* q = (u32*)&xs[grp * XST + ln * 4];
                q[0] = q[1] = 0u;
            }
        }
    }

    // per-lane MFMA geometry
    const int lane = tid & 63, wave = tid >> 6;   // wave = j-block (0..5)
    const int lr = lane & 15;                     // m/n local index
    const int md = (lane >> 4) * 4;               // D row base
    const int lk = (lane >> 4) * 8;               // k base within 32-step
    const int jg = wave * 16 + lr;                // global feature j

    const float sA = gamma[jg] * rsqrtf(rvar[jg] + BN_EPS);
    const float sC = (b_in[jg] - rmean[jg]) * sA + beta[jg];
    const float Bo = b_out[jg];
    __syncthreads();

    // ---- GEMM1 (K = DIN) ----
    f32x4 acc0 = {0.f, 0.f, 0.f, 0.f}, acc1 = {0.f, 0.f, 0.f, 0.f};
    #pragma unroll
    for (int ks = 0; ks < DIN / 32; ++ks) {
        const int k0 = ks * 32 + lk;
        const bf16x8 b  = *(const bf16x8*)&wT[jg * XST + k0];
        const bf16x8 a0 = *(const bf16x8*)&xs[lr * XST + k0];
        const bf16x8 a1 = *(const bf16x8*)&xs[(16 + lr) * XST + k0];
        acc0 = __builtin_amdgcn_mfma_f32_16x16x32_bf16(a0, b, acc0, 0, 0, 0);
        acc1 = __builtin_amdgcn_mfma_f32_16x16x32_bf16(a1, b, acc1, 0, 0, 0);
    }

    // z = relu(BN(acc)) -> bf16 (kept in regs across barrier)
    u16 z0[4], z1[4];
    #pragma unroll
    for (int r = 0; r < 4; ++r) {
        z0[r] = (u16)f2bfb(fmaxf(fmaf(acc0[r], sA, sC), 0.0f));
        z1[r] = (u16)f2bfb(fmaxf(fmaf(acc1[r], sA, sC), 0.0f));
    }
    __syncthreads();                              // all GEMM1 reads of xs/wT done

    // z -> xs (D-layout scatter), wT <- w_out
    #pragma unroll
    for (int r = 0; r < 4; ++r) {
        xs[(md + r) * XST + jg]      = z0[r];
        xs[(16 + md + r) * XST + jg] = z1[r];
    }
    for (int i = tid; i < 96 * XST / 8; i += 384)
        ((uint4*)wT)[i] = ((const uint4*)wbg2)[i];
    __syncthreads();

    // ---- GEMM2 (K = 96) ----
    f32x4 o0 = {0.f, 0.f, 0.f, 0.f}, o1 = {0.f, 0.f, 0.f, 0.f};
    #pragma unroll
    for (int ks = 0; ks < 3; ++ks) {
        const int k0 = ks * 32 + lk;
        const bf16x8 b  = *(const bf16x8*)&wT[jg * XST + k0];
        const bf16x8 a0 = *(const bf16x8*)&xs[lr * XST + k0];
        const bf16x8 a1 = *(const bf16x8*)&xs[(16 + lr) * XST + k0];
        o0 = __builtin_amdgcn_mfma_f32_16x16x32_bf16(a0, b, o0, 0, 0, 0);
        o1 = __builtin_amdgcn_mfma_f32_16x16x32_bf16(a1, b, o1, 0, 0, 0);
    }

    u16 y0[4], y1[4];
    #pragma unroll
    for (int r = 0; r < 4; ++r) {
        y0[r] = (u16)f2bfb(fmaxf(o0[r] + Bo, 0.0f));
        y1[r] = (u16)f2bfb(fmaxf(o1[r] + Bo, 0.0f));
    }
    #pragma unroll
    for (int r = 0; r < 4; ++r) {
        const int n0 = nbase + md + r;
        if (n0 < Nn) out[(long)n0 * Hh + jg] = y0[r];
        const int n1 = nbase + 16 + md + r;
        if (n1 < Nn) out[(long)n1 * Hh + jg] = y1[r];
    }

    if constexpr (POOL) {
        __syncthreads();                          // GEMM2 xs reads done
        #pragma unroll
        for (int r = 0; r < 4; ++r) {
            xs[(md + r) * XST + jg]      = y0[r];
            xs[(16 + md + r) * XST + jg] = y1[r];
        }
        __syncthreads();
        if (tid < Hh) {
            const int j = tid;
            float acc = 0.0f;
            int bcur = batch[nbase];
            for (int r = 0; r < TILE; ++r) {
                const int node = nbase + r;
                if (node >= Nn) break;
                const int bb = batch[node];
                if (bb != bcur) {
                    atomicAdd(&pooled[(long)bcur * Hh + j], acc);
                    acc = 0.0f;
                    bcur = bb;
                }
                acc += bf2f(xs[r * XST + j]);
            }
            atomicAdd(&pooled[(long)bcur * Hh + j], acc);
        }
    }
}

// ---------------------------------------------------------------------------
// Head: out[b] = dot(pooled[b], head_w[rt[b]]) + head_b[rt[b]]
// ---------------------------------------------------------------------------
__global__ void head_kernel(const float* __restrict__ pooled, const int* __restrict__ rt,
                            const float* __restrict__ hw, const float* __restrict__ hb,
                            float* __restrict__ outv) {
    const int b = blockIdx.x;
    const int lane = threadIdx.x;
    const int t = rt[b];
    const float* pp = pooled + (long)b * Hh;
    const float* wp = hw + (long)t * Hh;
    float s = 0.0f;
    for (int j = lane; j < Hh; j += 64) s += pp[j] * wp[j];
    #pragma unroll
    for (int off = 32; off > 0; off >>= 1) s += __shfl_down(s, off, 64);
    if (lane == 0) outv[b] = s + hb[t];
}

// ---------------------------------------------------------------------------
extern "C" void kernel_launch(void* const* d_in, const int* in_sizes, int n_in,
                              void* d_out, int out_size, void* d_ws, size_t ws_size,
                              hipStream_t stream) {
    const float* x     = (const float*)d_in[0];
    const int*   ei    = (const int*)d_in[1];      // [2, E] flattened int32
    const int*   src   = ei;
    const int*   dst   = ei + Ee;
    const int*   batch = (const int*)d_in[2];
    const int*   rt    = (const int*)d_in[3];

    const float* P[3][8];
    for (int l = 0; l < 3; ++l)
        for (int p = 0; p < 8; ++p)
            P[l][p] = (const float*)d_in[4 + l * 8 + p];
    const float* head_w = (const float*)d_in[28];
    const float* head_b = (const float*)d_in[29];

    // Workspace layout
    const size_t NH = (size_t)Nn * Hh;
    u16*   tA      = (u16*)d_ws;                       // N*H bf16
    u16*   tB      = tA + NH;                          // N*H bf16
    u16*   xb      = tB + NH;                          // N*INF bf16
    u16*   wball   = xb + (size_t)Nn * INF;            // WB_TOT u16 (transposed tables)
    float* pooled  = (float*)(wball + WB_TOT);         // B*H fp32
    int*   rowptr  = (int*)(pooled + (size_t)Bb * Hh); // N+1 ints
    int*   counts  = rowptr + Nn + 1;                  // NBIN*P1B ints
    int*   binbase = counts + NBIN * P1B;              // NBIN ints
    int*   bintot  = binbase + NBIN;                   // NBIN ints
    u16*   csr     = (u16*)(bintot + NBIN);            // E u16
    // binbuf (16.0 MB) overlays tA+tB (19.2 MB) — both dead during CSR build
    u32*   binbuf  = (u32*)tA;
    float* out     = (float*)d_out;

    const dim3 blk256(256), blk384(384), blk512(512);
    const int GRID_L = (Nn + 31) / 32;                 // 1563

    // ----- init (x/w tables + zero bintot/pooled) ; build CSR -----
    init_kernel<<<782 + (WB_TOT / 2 + 255) / 256, blk256, 0, stream>>>(
        x, xb, P[0][0], P[0][6], P[1][0], P[1][6], P[2][0], P[2][6], wball,
        bintot, pooled);
    p1_bin_kernel<<<P1B, blk256, 0, stream>>>(src, dst, binbuf, counts, bintot);
    p2_binscan_kernel<<<1, blk512, 0, stream>>>(bintot, binbase, rowptr);
    p3_binsort_kernel<<<NBIN, blk256, 0, stream>>>(binbuf, counts, binbase, rowptr, csr);

    // ----- Layer 1: xb -> tA -----
    layer_kernel<INF, false><<<GRID_L, blk384, 0, stream>>>(xb, rowptr, csr,
        wball + 0 * WMAT, wball + 1 * WMAT,
        P[0][1], P[0][2], P[0][3], P[0][4], P[0][5], P[0][7], tA, nullptr, nullptr);

    // ----- Layer 2: tA -> tB -----
    layer_kernel<Hh, false><<<GRID_L, blk384, 0, stream>>>(tA, rowptr, csr,
        wball + 2 * WMAT, wball + 3 * WMAT,
        P[1][1], P[1][2], P[1][3], P[1][4], P[1][5], P[1][7], tB, nullptr, nullptr);

    // ----- Layer 3 (+fused pool): tB -> tA, pooled -----
    layer_kernel<Hh, true><<<GRID_L, blk384, 0, stream>>>(tB, rowptr, csr,
        wball + 4 * WMAT, wball + 5 * WMAT,
        P[2][1], P[2][2], P[2][3], P[2][4], P[2][5], P[2][7], tA, batch, pooled);

    // ----- Head -----
    head_kernel<<<Bb, 64, 0, stream>>>(pooled, rt, head_w, head_b, out);
}

// Round 20
// 147.289 us; speedup vs baseline: 1.1054x; 1.1054x over previous
//
#include <hip/hip_runtime.h>

using u16 = unsigned short;
using u32 = unsigned int;
using u64 = unsigned long long;

typedef __attribute__((ext_vector_type(8))) short bf16x8;
typedef __attribute__((ext_vector_type(4))) float f32x4;

// Problem constants (from reference)
constexpr int Nn  = 50000;   // nodes
constexpr int Ee  = 800000;  // edges
constexpr int Bb  = 256;     // graphs
constexpr int INF = 32;      // input feature dim
constexpr int Hh  = 96;      // hidden dim
constexpr float BN_EPS = 1e-5f;

// Binned CSR build parameters
constexpr int BINW = 128;                      // nodes per bin
constexpr int NBIN = (Nn + BINW - 1) / BINW;   // 391
constexpr int P1B  = 256;                      // pass-1 blocks
constexpr int EPB  = Ee / P1B;                 // 3125 edges per block (exact)
constexpr int CAP  = 40;                       // per (block,bin) capacity (mean 8, ~8e-15 tail)
constexpr int P3IT = P1B * CAP / 256;          // 40 iterations per p3 thread

// Transposed bf16 weight tables: wT[j][k], k-contiguous, row stride 104 u16.
constexpr int WROW   = 104;
constexpr int WMAT   = 96 * WROW;              // 9984 u16 per matrix
constexpr int WB_TOT = 6 * WMAT;               // 59904 u16

// ---------------- bf16 helpers (rne) ----------------
__device__ __forceinline__ float bfL(u32 u) { return __uint_as_float(u << 16); }
__device__ __forceinline__ float bfH(u32 u) { return __uint_as_float(u & 0xFFFF0000u); }
__device__ __forceinline__ u32 f2bfb(float f) {            // rounded bf16 bits (low 16)
    u32 b = __float_as_uint(f);
    return (b + 0x7FFFu + ((b >> 16) & 1u)) >> 16;
}
__device__ __forceinline__ float bf2f(u16 u) { return __uint_as_float(((u32)u) << 16); }

// ---------------------------------------------------------------------------
// x -> bf16 table (N x 32). Also zeroes bintot (391 ints) and pooled
// (Bb*Hh fp32) — replaces two pathologically slow fillBuffer stream nodes.
// ---------------------------------------------------------------------------
__global__ void x2bf_init_kernel(const float* __restrict__ x, u16* __restrict__ xb,
                                 int* __restrict__ bintot, float* __restrict__ pooled) {
    const int gid = blockIdx.x * 256 + threadIdx.x;
    if (gid < NBIN) bintot[gid] = 0;
    if (gid < Bb * Hh) pooled[gid] = 0.0f;

    const int total = Nn * INF / 8;
    for (int i = gid; i < total; i += gridDim.x * 256) {
        const float4 a = ((const float4*)x)[2 * i];
        const float4 b = ((const float4*)x)[2 * i + 1];
        uint4 R;
        R.x = f2bfb(a.x) | (f2bfb(a.y) << 16);
        R.y = f2bfb(a.z) | (f2bfb(a.w) << 16);
        R.z = f2bfb(b.x) | (f2bfb(b.y) << 16);
        R.w = f2bfb(b.z) | (f2bfb(b.w) << 16);
        ((uint4*)xb)[i] = R;
    }
}

// ---------------------------------------------------------------------------
// Weights -> bf16 TRANSPOSED: wT[j][k] = w[k][j], row stride WROW, zero-pad.
// ---------------------------------------------------------------------------
__global__ void w2bf_kernel(const float* __restrict__ w1i, const float* __restrict__ w1o,
                            const float* __restrict__ w2i, const float* __restrict__ w2o,
                            const float* __restrict__ w3i, const float* __restrict__ w3o,
                            u16* __restrict__ wb) {
    const int i = blockIdx.x * 256 + threadIdx.x;   // u32 word index
    if (i >= WB_TOT / 2) return;
    const int mat = i / (WMAT / 2);
    const int rem = i % (WMAT / 2);
    const int j   = rem / (WROW / 2);
    const int k   = (rem % (WROW / 2)) * 2;
    const float* src; int din;
    switch (mat) {
        case 0: src = w1i; din = 32; break;
        case 1: src = w1o; din = 96; break;
        case 2: src = w2i; din = 96; break;
        case 3: src = w2o; din = 96; break;
        case 4: src = w3i; din = 96; break;
        default: src = w3o; din = 96; break;
    }
    const u32 lo = (k     < din) ? f2bfb(src[(long)k * 96 + j])       : 0u;
    const u32 hi = (k + 1 < din) ? f2bfb(src[(long)(k + 1) * 96 + j]) : 0u;
    ((u32*)wb)[i] = lo | (hi << 16);
}

// ---------------------------------------------------------------------------
// CSR build pass 1: bin edges into per-(block,bin) private regions.
// ---------------------------------------------------------------------------
__global__ __launch_bounds__(256)
void p1_bin_kernel(const int* __restrict__ src, const int* __restrict__ dst,
                   u32* __restrict__ binbuf, int* __restrict__ counts,
                   int* __restrict__ bintot) {
    __shared__ int cur[NBIN];
    const int b = blockIdx.x, tid = threadIdx.x;
    for (int k = tid; k < NBIN; k += 256) cur[k] = 0;
    __syncthreads();
    const long e0 = (long)b * EPB;
    for (int i = tid; i < EPB; i += 256) {
        const long e = e0 + i;
        const int d = dst[e];
        const int k = d >> 7;                              // BINW = 128
        const int pos = atomicAdd(&cur[k], 1);
        binbuf[((long)b * NBIN + k) * CAP + pos] = ((u32)(d & 127) << 16) | (u32)src[e];
    }
    __syncthreads();
    for (int k = tid; k < NBIN; k += 256) {
        const int c = cur[k];
        counts[k * P1B + b] = c;
        if (c) atomicAdd(&bintot[k], c);
    }
}

// ---------------------------------------------------------------------------
// CSR build pass 2: scan of bintot -> binbase; rowptr[N] = E. 512 threads.
// ---------------------------------------------------------------------------
__global__ void p2_binscan_kernel(const int* __restrict__ bintot, int* __restrict__ binbase,
                                  int* __restrict__ rowptr) {
    __shared__ int ps[512];
    const int t = threadIdx.x;
    const int v = (t < NBIN) ? bintot[t] : 0;
    ps[t] = v;
    __syncthreads();
    for (int d = 1; d < 512; d <<= 1) {
        int u = (t >= d) ? ps[t - d] : 0;
        __syncthreads();
        if (t >= d) ps[t] += u;
        __syncthreads();
    }
    if (t < NBIN) binbase[t] = ps[t] - v;   // exclusive prefix
    if (t == 0) rowptr[Nn] = Ee;
}

// ---------------------------------------------------------------------------
// CSR build pass 3: one block per bin; payloads register-cached.
// ---------------------------------------------------------------------------
__global__ __launch_bounds__(256)
void p3_binsort_kernel(const u32* __restrict__ binbuf, const int* __restrict__ counts,
                       const int* __restrict__ binbase, int* __restrict__ rowptr,
                       u16* __restrict__ csr) {
    __shared__ int cnt[P1B];
    __shared__ int lhist[BINW];
    __shared__ int lpref[BINW];
    const int k = blockIdx.x, tid = threadIdx.x;

    for (int b = tid; b < P1B; b += 256) cnt[b] = counts[k * P1B + b];
    if (tid < BINW) lhist[tid] = 0;
    __syncthreads();

    u32 pv[P3IT];
    u64 vmask = 0;
    #pragma unroll
    for (int it = 0; it < P3IT; ++it) {
        const int flat = tid + it * 256;
        const int b = flat / CAP, i = flat % CAP;
        if (i < cnt[b]) {
            const u32 v = binbuf[((long)b * NBIN + k) * CAP + i];
            pv[it] = v;
            vmask |= 1ull << it;
            atomicAdd(&lhist[v >> 16], 1);
        }
    }
    __syncthreads();

    if (tid < BINW) lpref[tid] = lhist[tid];
    __syncthreads();
    for (int d = 1; d < BINW; d <<= 1) {
        int u = 0;
        if (tid < BINW && tid >= d) u = lpref[tid - d];
        __syncthreads();
        if (tid < BINW && tid >= d) lpref[tid] += u;
        __syncthreads();
    }
    if (tid < BINW) lpref[tid] -= lhist[tid];

    const int base = binbase[k];
    const int node = k * BINW + tid;
    if (tid < BINW && node < Nn) rowptr[node] = base + lpref[tid];
    if (tid < BINW) lhist[tid] = 0;                 // reuse as cursor
    __syncthreads();

    #pragma unroll
    for (int it = 0; it < P3IT; ++it) {
        if (vmask & (1ull << it)) {
            const u32 v = pv[it];
            const int dl = v >> 16;
            const int pos = base + lpref[dl] + atomicAdd(&lhist[dl], 1);
            csr[pos] = (u16)(v & 0xFFFFu);
        }
    }
}

// ---------------------------------------------------------------------------
// FULL GIN LAYER with MFMA GEMMs. 32-node tile, 384 threads (6 waves).
// Gather 8x-unrolled (scalar index loads — vectorized variant regressed).
// POOL=true (layer 3): fused graph pooling.
// ---------------------------------------------------------------------------
template<int DIN, bool POOL>
__global__ __launch_bounds__(384, 4)
void layer_kernel(const u16* __restrict__ hsrc, const int* __restrict__ rowptr,
                  const u16* __restrict__ csr,
                  const u16* __restrict__ wbg1, const u16* __restrict__ wbg2,
                  const float* __restrict__ b_in,
                  const float* __restrict__ gamma, const float* __restrict__ beta,
                  const float* __restrict__ rmean, const float* __restrict__ rvar,
                  const float* __restrict__ b_out,
                  u16* __restrict__ out,
                  const int* __restrict__ batch, float* __restrict__ pooled) {
    constexpr int TILE = 32;
    constexpr int XST  = 104;                 // u16 stride (208B rows)
    __shared__ __align__(16) u16 wT[96 * XST];
    __shared__ __align__(16) u16 xs[TILE * XST];

    const int tid = threadIdx.x;
    const int nbase = blockIdx.x * TILE;

    // stage wT(w_in)
    for (int i = tid; i < 96 * XST / 8; i += 384)
        ((uint4*)wT)[i] = ((const uint4*)wbg1)[i];

    // ---- gather phase: 12 lanes per node (uint4 each), 8x edge unroll ----
    {
        const int grp = tid / 12, ln = tid % 12;
        const int node = nbase + grp;
        if (node < Nn) {
            const int e0 = rowptr[node], e1 = rowptr[node + 1];
            if constexpr (DIN == 96) {
                const uint4* h4 = (const uint4*)hsrc;     // row = 12 uint4
                float a0, a1, a2, a3, a4, a5, a6, a7;
                {
                    const uint4 U = h4[(long)node * 12 + ln];
                    a0 = bfL(U.x); a1 = bfH(U.x); a2 = bfL(U.y); a3 = bfH(U.y);
                    a4 = bfL(U.z); a5 = bfH(U.z); a6 = bfL(U.w); a7 = bfH(U.w);
                }
                int e = e0;
                for (; e + 8 <= e1; e += 8) {
                    uint4 U[8];
                    #pragma unroll
                    for (int q = 0; q < 8; ++q) U[q] = h4[(long)csr[e + q] * 12 + ln];
                    #pragma unroll
                    for (int q = 0; q < 8; ++q) {
                        a0 += bfL(U[q].x); a1 += bfH(U[q].x);
                        a2 += bfL(U[q].y); a3 += bfH(U[q].y);
                        a4 += bfL(U[q].z); a5 += bfH(U[q].z);
                        a6 += bfL(U[q].w); a7 += bfH(U[q].w);
                    }
                }
                for (; e + 2 <= e1; e += 2) {
                    const uint4 Ua = h4[(long)csr[e] * 12 + ln];
                    const uint4 Ub = h4[(long)csr[e + 1] * 12 + ln];
                    a0 += bfL(Ua.x); a1 += bfH(Ua.x); a2 += bfL(Ua.y); a3 += bfH(Ua.y);
                    a4 += bfL(Ua.z); a5 += bfH(Ua.z); a6 += bfL(Ua.w); a7 += bfH(Ua.w);
                    a0 += bfL(Ub.x); a1 += bfH(Ub.x); a2 += bfL(Ub.y); a3 += bfH(Ub.y);
                    a4 += bfL(Ub.z); a5 += bfH(Ub.z); a6 += bfL(Ub.w); a7 += bfH(Ub.w);
                }
                if (e < e1) {
                    const uint4 U = h4[(long)csr[e] * 12 + ln];
                    a0 += bfL(U.x); a1 += bfH(U.x); a2 += bfL(U.y); a3 += bfH(U.y);
                    a4 += bfL(U.z); a5 += bfH(U.z); a6 += bfL(U.w); a7 += bfH(U.w);
                }
                u32* xp = (u32*)&xs[grp * XST + ln * 8];
                xp[0] = f2bfb(a0) | (f2bfb(a1) << 16);
                xp[1] = f2bfb(a2) | (f2bfb(a3) << 16);
                xp[2] = f2bfb(a4) | (f2bfb(a5) << 16);
                xp[3] = f2bfb(a6) | (f2bfb(a7) << 16);
            } else {                                      // DIN == 32: 8 lanes/node
                if (ln < 8) {
                    const uint2* h2 = (const uint2*)hsrc; // row = 8 uint2
                    float a0, a1, a2, a3;
                    {
                        const uint2 U = h2[(long)node * 8 + ln];
                        a0 = bfL(U.x); a1 = bfH(U.x); a2 = bfL(U.y); a3 = bfH(U.y);
                    }
                    int e = e0;
                    for (; e + 8 <= e1; e += 8) {
                        uint2 U[8];
                        #pragma unroll
                        for (int q = 0; q < 8; ++q) U[q] = h2[(long)csr[e + q] * 8 + ln];
                        #pragma unroll
                        for (int q = 0; q < 8; ++q) {
                            a0 += bfL(U[q].x); a1 += bfH(U[q].x);
                            a2 += bfL(U[q].y); a3 += bfH(U[q].y);
                        }
                    }
                    for (; e < e1; ++e) {
                        const uint2 U = h2[(long)csr[e] * 8 + ln];
                        a0 += bfL(U.x); a1 += bfH(U.x); a2 += bfL(U.y); a3 += bfH(U.y);
                    }
                    u32* xp = (u32*)&xs[grp * XST + ln * 4];
                    xp[0] = f2bfb(a0) | (f2bfb(a1) << 16);
                    xp[1] = f2bfb(a2) | (f2bfb(a3) << 16);
                }
            }
        } else {
            if constexpr (DIN == 96) {
                u32* xp = (u32*)&xs[grp * XST + ln * 8];
                xp[0] = xp[1] = xp[2] = xp[3] = 0u;
            } else if (ln < 8) {
                u32* q = (u32*)&xs[grp * XST + ln * 4];
                q[0] = q[1] = 0u;
            }
        }
    }

    // per-lane MFMA geometry
    const int lane = tid & 63, wave = tid >> 6;   // wave = j-block (0..5)
    const int lr = lane & 15;                     // m/n local index
    const int md = (lane >> 4) * 4;               // D row base
    const int lk = (lane >> 4) * 8;               // k base within 32-step
    const int jg = wave * 16 + lr;                // global feature j

    const float sA = gamma[jg] * rsqrtf(rvar[jg] + BN_EPS);
    const float sC = (b_in[jg] - rmean[jg]) * sA + beta[jg];
    const float Bo = b_out[jg];
    __syncthreads();

    // ---- GEMM1 (K = DIN) ----
    f32x4 acc0 = {0.f, 0.f, 0.f, 0.f}, acc1 = {0.f, 0.f, 0.f, 0.f};
    #pragma unroll
    for (int ks = 0; ks < DIN / 32; ++ks) {
        const int k0 = ks * 32 + lk;
        const bf16x8 b  = *(const bf16x8*)&wT[jg * XST + k0];
        const bf16x8 a0 = *(const bf16x8*)&xs[lr * XST + k0];
        const bf16x8 a1 = *(const bf16x8*)&xs[(16 + lr) * XST + k0];
        acc0 = __builtin_amdgcn_mfma_f32_16x16x32_bf16(a0, b, acc0, 0, 0, 0);
        acc1 = __builtin_amdgcn_mfma_f32_16x16x32_bf16(a1, b, acc1, 0, 0, 0);
    }

    // z = relu(BN(acc)) -> bf16 (kept in regs across barrier)
    u16 z0[4], z1[4];
    #pragma unroll
    for (int r = 0; r < 4; ++r) {
        z0[r] = (u16)f2bfb(fmaxf(fmaf(acc0[r], sA, sC), 0.0f));
        z1[r] = (u16)f2bfb(fmaxf(fmaf(acc1[r], sA, sC), 0.0f));
    }
    __syncthreads();                              // all GEMM1 reads of xs/wT done

    // z -> xs (D-layout scatter), wT <- w_out
    #pragma unroll
    for (int r = 0; r < 4; ++r) {
        xs[(md + r) * XST + jg]      = z0[r];
        xs[(16 + md + r) * XST + jg] = z1[r];
    }
    for (int i = tid; i < 96 * XST / 8; i += 384)
        ((uint4*)wT)[i] = ((const uint4*)wbg2)[i];
    __syncthreads();

    // ---- GEMM2 (K = 96) ----
    f32x4 o0 = {0.f, 0.f, 0.f, 0.f}, o1 = {0.f, 0.f, 0.f, 0.f};
    #pragma unroll
    for (int ks = 0; ks < 3; ++ks) {
        const int k0 = ks * 32 + lk;
        const bf16x8 b  = *(const bf16x8*)&wT[jg * XST + k0];
        const bf16x8 a0 = *(const bf16x8*)&xs[lr * XST + k0];
        const bf16x8 a1 = *(const bf16x8*)&xs[(16 + lr) * XST + k0];
        o0 = __builtin_amdgcn_mfma_f32_16x16x32_bf16(a0, b, o0, 0, 0, 0);
        o1 = __builtin_amdgcn_mfma_f32_16x16x32_bf16(a1, b, o1, 0, 0, 0);
    }

    u16 y0[4], y1[4];
    #pragma unroll
    for (int r = 0; r < 4; ++r) {
        y0[r] = (u16)f2bfb(fmaxf(o0[r] + Bo, 0.0f));
        y1[r] = (u16)f2bfb(fmaxf(o1[r] + Bo, 0.0f));
    }
    #pragma unroll
    for (int r = 0; r < 4; ++r) {
        const int n0 = nbase + md + r;
        if (n0 < Nn) out[(long)n0 * Hh + jg] = y0[r];
        const int n1 = nbase + 16 + md + r;
        if (n1 < Nn) out[(long)n1 * Hh + jg] = y1[r];
    }

    if constexpr (POOL) {
        __syncthreads();                          // GEMM2 xs reads done
        #pragma unroll
        for (int r = 0; r < 4; ++r) {
            xs[(md + r) * XST + jg]      = y0[r];
            xs[(16 + md + r) * XST + jg] = y1[r];
        }
        __syncthreads();
        if (tid < Hh) {
            const int j = tid;
            float acc = 0.0f;
            int bcur = batch[nbase];
            for (int r = 0; r < TILE; ++r) {
                const int node = nbase + r;
                if (node >= Nn) break;
                const int bb = batch[node];
                if (bb != bcur) {
                    atomicAdd(&pooled[(long)bcur * Hh + j], acc);
                    acc = 0.0f;
                    bcur = bb;
                }
                acc += bf2f(xs[r * XST + j]);
            }
            atomicAdd(&pooled[(long)bcur * Hh + j], acc);
        }
    }
}

// ---------------------------------------------------------------------------
// Head: out[b] = dot(pooled[b], head_w[rt[b]]) + head_b[rt[b]]
// ---------------------------------------------------------------------------
__global__ void head_kernel(const float* __restrict__ pooled, const int* __restrict__ rt,
                            const float* __restrict__ hw, const float* __restrict__ hb,
                            float* __restrict__ outv) {
    const int b = blockIdx.x;
    const int lane = threadIdx.x;
    const int t = rt[b];
    const float* pp = pooled + (long)b * Hh;
    const float* wp = hw + (long)t * Hh;
    float s = 0.0f;
    for (int j = lane; j < Hh; j += 64) s += pp[j] * wp[j];
    #pragma unroll
    for (int off = 32; off > 0; off >>= 1) s += __shfl_down(s, off, 64);
    if (lane == 0) outv[b] = s + hb[t];
}

// ---------------------------------------------------------------------------
extern "C" void kernel_launch(void* const* d_in, const int* in_sizes, int n_in,
                              void* d_out, int out_size, void* d_ws, size_t ws_size,
                              hipStream_t stream) {
    const float* x     = (const float*)d_in[0];
    const int*   ei    = (const int*)d_in[1];      // [2, E] flattened int32
    const int*   src   = ei;
    const int*   dst   = ei + Ee;
    const int*   batch = (const int*)d_in[2];
    const int*   rt    = (const int*)d_in[3];

    const float* P[3][8];
    for (int l = 0; l < 3; ++l)
        for (int p = 0; p < 8; ++p)
            P[l][p] = (const float*)d_in[4 + l * 8 + p];
    const float* head_w = (const float*)d_in[28];
    const float* head_b = (const float*)d_in[29];

    // Workspace layout
    const size_t NH = (size_t)Nn * Hh;
    u16*   tA      = (u16*)d_ws;                       // N*H bf16
    u16*   tB      = tA + NH;                          // N*H bf16
    u16*   xb      = tB + NH;                          // N*INF bf16
    u16*   wball   = xb + (size_t)Nn * INF;            // WB_TOT u16 (transposed tables)
    float* pooled  = (float*)(wball + WB_TOT);         // B*H fp32
    int*   rowptr  = (int*)(pooled + (size_t)Bb * Hh); // N+1 ints
    int*   counts  = rowptr + Nn + 1;                  // NBIN*P1B ints
    int*   binbase = counts + NBIN * P1B;              // NBIN ints
    int*   bintot  = binbase + NBIN;                   // NBIN ints
    u16*   csr     = (u16*)(bintot + NBIN);            // E u16
    // binbuf (16.0 MB) overlays tA+tB (19.2 MB) — both dead during CSR build
    u32*   binbuf  = (u32*)tA;
    float* out     = (float*)d_out;

    const dim3 blk256(256), blk384(384), blk512(512);
    const int GRID_L = (Nn + 31) / 32;                 // 1563

    // ----- precompute tables (+ zero bintot/pooled) ; build CSR -----
    x2bf_init_kernel<<<782, blk256, 0, stream>>>(x, xb, bintot, pooled);
    w2bf_kernel<<<(WB_TOT / 2 + 255) / 256, blk256, 0, stream>>>(
        P[0][0], P[0][6], P[1][0], P[1][6], P[2][0], P[2][6], wball);
    p1_bin_kernel<<<P1B, blk256, 0, stream>>>(src, dst, binbuf, counts, bintot);
    p2_binscan_kernel<<<1, blk512, 0, stream>>>(bintot, binbase, rowptr);
    p3_binsort_kernel<<<NBIN, blk256, 0, stream>>>(binbuf, counts, binbase, rowptr, csr);

    // ----- Layer 1: xb -> tA -----
    layer_kernel<INF, false><<<GRID_L, blk384, 0, stream>>>(xb, rowptr, csr,
        wball + 0 * WMAT, wball + 1 * WMAT,
        P[0][1], P[0][2], P[0][3], P[0][4], P[0][5], P[0][7], tA, nullptr, nullptr);

    // ----- Layer 2: tA -> tB -----
    layer_kernel<Hh, false><<<GRID_L, blk384, 0, stream>>>(tA, rowptr, csr,
        wball + 2 * WMAT, wball + 3 * WMAT,
        P[1][1], P[1][2], P[1][3], P[1][4], P[1][5], P[1][7], tB, nullptr, nullptr);

    // ----- Layer 3 (+fused pool): tB -> tA, pooled -----
    layer_kernel<Hh, true><<<GRID_L, blk384, 0, stream>>>(tB, rowptr, csr,
        wball + 4 * WMAT, wball + 5 * WMAT,
        P[2][1], P[2][2], P[2][3], P[2][4], P[2][5], P[2][7], tA, batch, pooled);

    // ----- Head -----
    head_kernel<<<Bb, 64, 0, stream>>>(pooled, rt, head_w, head_b, out);
}